// Round 6
// baseline (49.401 us; speedup 1.0000x reference)
//
#include <hip/hip_runtime.h>

#define BIGV 1.0e6f

// ---------------------------------------------------------------------------
// Kernel A: per (b, which) build a value-ascending (bucketed) candidate list.
// 16 blocks x 256 threads. Bucket k holds values in [k/256, (k+1)/256).
// Entry: uint2 { float_bits(v), idx }  with idx = i*64 + j.
// Buckets are emitted in ascending order; within-bucket order arbitrary.
// ---------------------------------------------------------------------------
__global__ __launch_bounds__(256) void build_lists(
    const float* __restrict__ gt, const float* __restrict__ pred,
    uint2* __restrict__ lists)
{
    __shared__ int cnt[256];
    __shared__ int off[256];

    const int blk   = blockIdx.x;    // 0..15
    const int b     = blk >> 1;
    const int which = blk & 1;       // 0 = pred list (for m1), 1 = gt list (for m2)
    const float* __restrict__ src = (which ? gt : pred) + b * 4096;
    uint2* __restrict__ out = lists + blk * 4096;
    const int tid = threadIdx.x;

    cnt[tid] = 0;
    __syncthreads();

    float vals[16];
    int   bkt[16];
    #pragma unroll
    for (int k = 0; k < 16; ++k) {
        const int idx = tid + (k << 8);
        const float v = src[idx];
        vals[k] = v;
        int bb = (int)(v * 256.0f);
        bb = bb > 255 ? 255 : (bb < 0 ? 0 : bb);
        bkt[k] = bb;
        atomicAdd(&cnt[bb], 1);
    }
    __syncthreads();

    // Exclusive prefix over the 256 bucket counts (wave 0, 4 chunks of 64).
    if (tid < 64) {
        int carry = 0;
        #pragma unroll
        for (int k = 0; k < 4; ++k) {
            const int x = cnt[k * 64 + tid];
            int incl = x;
            #pragma unroll
            for (int s = 1; s < 64; s <<= 1) {
                int y = __shfl_up(incl, s, 64);
                if (tid >= s) incl += y;
            }
            off[k * 64 + tid] = carry + incl - x;
            carry += __shfl(incl, 63, 64);   // chunk total from lane 63
        }
    }
    __syncthreads();

    #pragma unroll
    for (int k = 0; k < 16; ++k) {
        const int idx  = tid + (k << 8);
        const int slot = atomicAdd(&off[bkt[k]], 1);
        out[slot] = make_uint2(__float_as_uint(vals[k]), (unsigned)idx);
    }
}

// ---------------------------------------------------------------------------
// Kernel B: one block per (b, h), 128 threads = 2 waves.
// Wave 0 walks the pred list (m1, + loss sum + c1), wave 1 the gt list (m2, c2).
// Each lane is query (h, w). Candidates arrive in ascending value buckets;
// since f = v*(1+d) >= v >= bucket_floor, the wave stops as soon as
// all lanes have m <= bucket_floor(next entry). Exact early termination.
// ---------------------------------------------------------------------------
__global__ __launch_bounds__(128) void imageloss_query(
    const float* __restrict__ gt, const float* __restrict__ pred,
    const uint2* __restrict__ lists, float* __restrict__ ws)
{
    const int blk  = blockIdx.x;    // 0..511
    const int b    = blk >> 6;
    const int h    = blk & 63;
    const int tid  = threadIdx.x;
    const int w    = tid & 63;
    const int wave = tid >> 6;      // 0: pred list; 1: gt list

    const uint2* __restrict__ list = lists + (b * 2 + wave) * 4096;
    const float hf = (float)h, wf = (float)w;

    float m = 3.4e38f;
    int e = 0;
    while (true) {
        int e_end = e + 16;
        if (e_end > 4096) e_end = 4096;
        for (; e < e_end; ++e) {
            const uint2 ent = list[e];          // wave-uniform broadcast load
            const float v   = __uint_as_float(ent.x);
            const int   idx = (int)ent.y;
            const float dx  = hf - (float)(idx >> 6);
            const float dy  = wf - (float)(idx & 63);
            const float d   = __builtin_amdgcn_sqrtf(fmaf(dy, dy, dx * dx));
            m = fminf(m, fmaf(v, d, v));        // v*(1+d)
        }
        if (e >= 4096) break;
        const float vn = __uint_as_float(list[e].x);
        const float lb = floorf(vn * 256.0f) * (1.0f / 256.0f); // == bucket/256
        if (__all(m <= lb)) break;              // no lane can improve: done
    }

    const float g = gt[b * 4096 + h * 64 + w];
    const float p = pred[b * 4096 + h * 64 + w];

    if (wave == 0) {
        const float gth = g + (1.0f - g) * BIGV;
        float c1 = gth * m;                     // min_dist contribution
        float df = g - p;
        float sq = df * df;                     // loss contribution
        #pragma unroll
        for (int off = 32; off > 0; off >>= 1) {
            c1 += __shfl_down(c1, off, 64);
            sq += __shfl_down(sq, off, 64);
        }
        if (w == 0) {
            atomicAdd(&ws[0], sq);
            atomicAdd(&ws[1], c1);
        }
    } else {
        const float pth = p + (1.0f - p) * BIGV;
        float c2 = pth * m;                     // min_dist_inv contribution
        #pragma unroll
        for (int off = 32; off > 0; off >>= 1)
            c2 += __shfl_down(c2, off, 64);
        if (w == 0) atomicAdd(&ws[2], c2);
    }
}

__global__ void imageloss_final(const float* __restrict__ ws, float* __restrict__ out)
{
    out[0] = ws[0] * (1.0f / 512.0f);
    out[1] = ws[1] * (1.0f / 32768.0f);
    out[2] = ws[2] * (1.0f / 32768.0f);
}

extern "C" void kernel_launch(void* const* d_in, const int* in_sizes, int n_in,
                              void* d_out, int out_size, void* d_ws, size_t ws_size,
                              hipStream_t stream)
{
    const float* gt   = (const float*)d_in[0];
    const float* pred = (const float*)d_in[1];
    float* out = (float*)d_out;
    float* ws  = (float*)d_ws;
    uint2* lists = (uint2*)((char*)d_ws + 1024);   // 16 lists x 4096 x 8 B

    hipMemsetAsync(ws, 0, 3 * sizeof(float), stream);
    build_lists<<<16, 256, 0, stream>>>(gt, pred, lists);
    imageloss_query<<<512, 128, 0, stream>>>(gt, pred, lists, ws);
    imageloss_final<<<1, 1, 0, stream>>>(ws, out);
}